// Round 7
// baseline (245.283 us; speedup 1.0000x reference)
//
#include <hip/hip_runtime.h>
#include <hip/hip_bf16.h>

constexpr int E     = 2048;   // edges
constexpr int NVARS = 512;    // variable nodes
constexpr int MAXS  = 20;     // max slots per rank (= max var degree supported)
constexpr int NBMAX = MAXS / 4;
constexpr int DBINS = 32;     // degree bins for counting sort (deg ~ Poisson(4))
constexpr int TB    = 8;      // batch rows per block in main kernel
constexpr int NT    = 512;    // threads per block in main kernel

// RNE float -> bf16 (kept in HIGH 16 bits).
__device__ __forceinline__ unsigned bf16hi(float f) {
    const unsigned uu = __float_as_uint(f);
    return (uu + 0x7FFFu + ((uu >> 16) & 1u)) & 0xFFFF0000u;
}
__device__ __forceinline__ unsigned pk2(float a, float b) {
    return (bf16hi(a) >> 16) | bf16hi(b);
}
__device__ __forceinline__ float bl(unsigned q) { return __uint_as_float(q << 16); }
__device__ __forceinline__ float bh(unsigned q) { return __uint_as_float(q & 0xFFFF0000u); }

// ---------------------------------------------------------------------------
// kA: scan skip mask (4 MB) -> var(e) + fused skip weight. One nonzero per
// column => unique writer. grid (8, 32) x 256 threads, fully coalesced.
// ---------------------------------------------------------------------------
__global__ __launch_bounds__(256)
void k_vsrc(const float* __restrict__ skip_mask,
            const float* __restrict__ llr_w,
            unsigned short* __restrict__ vsrc,
            float* __restrict__ skw)
{
    const int col = blockIdx.x * 256 + threadIdx.x;
    const int v0  = blockIdx.y * (NVARS / 32);     // 16-row stripe
    for (int v = v0; v < v0 + NVARS / 32; ++v) {
        const float m = skip_mask[(size_t)v * E + col];
        if (m != 0.0f) {
            vsrc[col] = (unsigned short)v;
            skw [col] = m * llr_w[(size_t)v * E + col];
        }
    }
}

// ---------------------------------------------------------------------------
// kB: ONE build kernel, grid 32 x 64 (one thread per column). Each block
// redundantly (deterministically) computes: deg histogram over vsrc, counting
// sort of vars by (deg, var) -> varStartRank, then per column: scan vsrc for
// its var's members (ascending e = deterministic), rank = vstart + selfIdx.
// Ranks are contiguous per var and sorted by deg => wave-uniform fan-in in
// fused_main. Table slot j of rank r = member j (self gets weight 0).
// ---------------------------------------------------------------------------
__global__ __launch_bounds__(64)
void k_table(const unsigned short* __restrict__ vsrc,
             const float* __restrict__ skw,
             const float* __restrict__ odd_w,
             const float* __restrict__ u,
             const float* __restrict__ logits,
             unsigned int* __restrict__ tbl,
             float2* __restrict__ meta)
{
    __shared__ unsigned short vs[E];          // 4 KB
    __shared__ int deg[NVARS];                // 2 KB
    __shared__ int vstart[NVARS];             // 2 KB
    __shared__ int dbin[DBINS], nxt[DBINS];
    __shared__ unsigned short grp[64][MAXS];  // 2.5 KB

    const int tid = threadIdx.x;
    const int col = blockIdx.x * 64 + tid;

    for (int i = tid; i < E / 8; i += 64)
        ((uint4*)vs)[i] = ((const uint4*)vsrc)[i];
    for (int i = tid; i < NVARS; i += 64) deg[i] = 0;
    if (tid < DBINS) dbin[tid] = 0;
    __syncthreads();
    for (int i = tid; i < E; i += 64) atomicAdd(&deg[vs[i]], 1);
    __syncthreads();
    for (int i = tid; i < NVARS; i += 64) {
        const int d = deg[i];
        if (d > 0) atomicAdd(&dbin[d < DBINS ? d : DBINS - 1], 1);
    }
    __syncthreads();
    if (tid == 0) {                            // serial counting-sort setup
        int s = 0;
        for (int d = 0; d < DBINS; ++d) { nxt[d] = s; s += d * dbin[d]; }
        for (int v = 0; v < NVARS; ++v) {
            const int d = deg[v];
            if (d > 0) {
                const int db = d < DBINS ? d : DBINS - 1;
                vstart[v] = nxt[db];
                nxt[db] += d;
            }
        }
    }
    __syncthreads();

    // member scan: ascending edge order (deterministic)
    const unsigned v = vs[col];
    int cnt = 0, selfIdx = 0;
    const unsigned* vs32 = (const unsigned*)vs;
    for (int i2 = 0; i2 < E / 2; ++i2) {       // broadcast LDS reads
        const unsigned p = vs32[i2];
        const int e0 = 2 * i2, e1 = 2 * i2 + 1;
        if ((p & 0xFFFFu) == v) {
            if (e0 == col) selfIdx = cnt;
            if (cnt < MAXS) grp[tid][cnt] = (unsigned short)e0;
            ++cnt;
        }
        if ((p >> 16) == v) {
            if (e1 == col) selfIdx = cnt;
            if (cnt < MAXS) grp[tid][cnt] = (unsigned short)e1;
            ++cnt;
        }
    }
    const int d_eff = (cnt < MAXS) ? cnt : MAXS;
    const int sIdx  = (selfIdx < MAXS) ? selfIdx : MAXS - 1;
    const int nb    = (d_eff + 3) >> 2;
    const int rank  = vstart[v] + sIdx;

    meta[rank] = make_float2(skw[col],
                             __int_as_float(col | ((int)v << 11) | (nb << 20)));

    for (int j = 0; j < nb * 4; ++j) {
        unsigned ent = 0u;                     // pad / self slot: w = 0
        if (j < d_eff) {
            const int ep = grp[tid][j];
            if (ep != col) {
                const float sig = 1.0f / (1.0f + __expf(-logits[ep]));
                const float z   = (u[ep] < sig) ? 1.0f : 0.0f;
                const float ww  = odd_w[(size_t)ep * E + col] * z;
                ent = bf16hi(ww) | (unsigned)ep;
            }
        }
        tbl[((size_t)(j >> 2) * E + rank) * 4 + (j & 3)] = ent;
    }
}

// tanh(0.5*clip(s,-10,10)) = (e^c - 1)/(e^c + 1)
__device__ __forceinline__ float tanh_half_clip(float s) {
    float c = fminf(fmaxf(s, -10.0f), 10.0f);
    float t = __expf(c);
    return (t - 1.0f) * __frcp_rn(t + 1.0f);
}

// ---------------------------------------------------------------------------
// Main fused kernel. TB=8 rows; x/llr staged bf16 (8 rows per uint4 => ONE
// ds_read_b128 per gather entry). Ranks sorted by deg => wave-uniform nb.
// Outputs: stash bf16 pairs in registers, sync, reuse xs as 4 row-pair
// planes, sync, fully coalesced f32 stores. LDS = 40 KB -> 4 blocks/CU.
// ---------------------------------------------------------------------------
__global__ __launch_bounds__(NT, 8)
void fused_main(const float* __restrict__ x,          // [B, E]
                const float* __restrict__ llr,        // [B, NVARS]
                const unsigned int* __restrict__ tbl, // [NBMAX][E] uint4 blocks
                const float2* __restrict__ meta,      // [E] rank-major
                float* __restrict__ out)
{
    __shared__ uint4 xs[E];        // stage: packed x; later: out planes
    __shared__ uint4 ls[NVARS];

    const int b0 = blockIdx.x * TB;
    const int t  = threadIdx.x;

    {
        const float4* xr = (const float4*)(x + (size_t)b0 * E);
        const float4 r0 = xr[0 * (E / 4) + t];
        const float4 r1 = xr[1 * (E / 4) + t];
        const float4 r2 = xr[2 * (E / 4) + t];
        const float4 r3 = xr[3 * (E / 4) + t];
        const float4 r4 = xr[4 * (E / 4) + t];
        const float4 r5 = xr[5 * (E / 4) + t];
        const float4 r6 = xr[6 * (E / 4) + t];
        const float4 r7 = xr[7 * (E / 4) + t];
        xs[4 * t + 0] = make_uint4(pk2(r0.x, r1.x), pk2(r2.x, r3.x),
                                   pk2(r4.x, r5.x), pk2(r6.x, r7.x));
        xs[4 * t + 1] = make_uint4(pk2(r0.y, r1.y), pk2(r2.y, r3.y),
                                   pk2(r4.y, r5.y), pk2(r6.y, r7.y));
        xs[4 * t + 2] = make_uint4(pk2(r0.z, r1.z), pk2(r2.z, r3.z),
                                   pk2(r4.z, r5.z), pk2(r6.z, r7.z));
        xs[4 * t + 3] = make_uint4(pk2(r0.w, r1.w), pk2(r2.w, r3.w),
                                   pk2(r4.w, r5.w), pk2(r6.w, r7.w));
    }
    {
        const float* lr = llr + (size_t)b0 * NVARS;
        ls[t] = make_uint4(pk2(lr[t],             lr[NVARS + t]),
                           pk2(lr[2 * NVARS + t], lr[3 * NVARS + t]),
                           pk2(lr[4 * NVARS + t], lr[5 * NVARS + t]),
                           pk2(lr[6 * NVARS + t], lr[7 * NVARS + t]));
    }
    __syncthreads();

    unsigned st0[4], st1[4], st2[4], st3[4];   // bf16-pair stash per k
    int cols[4];

    #pragma unroll
    for (int k = 0; k < E / NT; ++k) {
        const int rk = k * NT + t;              // rank (sorted by deg)
        const float2 mt = meta[rk];
        const int vc  = __float_as_int(mt.y);
        const int col = vc & 0x7FF;
        const int v   = (vc >> 11) & 0x1FF;
        const int nb  = (vc >> 20) & 0xF;
        const float sk = mt.x;

        const uint4 lv = ls[v];
        float a0 = sk * bl(lv.x), a1 = sk * bh(lv.x);
        float a2 = sk * bl(lv.y), a3 = sk * bh(lv.y);
        float a4 = sk * bl(lv.z), a5 = sk * bh(lv.z);
        float a6 = sk * bl(lv.w), a7 = sk * bh(lv.w);

        const uint4* tq = (const uint4*)tbl + rk;   // coalesced (rank-major)
        for (int ib = 0; ib < nb; ++ib) {
            const uint4 g = tq[(size_t)ib * E];
            #pragma unroll
            for (int q = 0; q < 4; ++q) {
                const unsigned ent = (q == 0) ? g.x : (q == 1) ? g.y
                                   : (q == 2) ? g.z : g.w;
                const float wv = __uint_as_float(ent & 0xFFFF0000u);
                const int   s  = (int)(ent & 0x7FFu);
                const uint4 xv = xs[s];                  // one ds_read_b128
                a0 += wv * bl(xv.x); a1 += wv * bh(xv.x);
                a2 += wv * bl(xv.y); a3 += wv * bh(xv.y);
                a4 += wv * bl(xv.z); a5 += wv * bh(xv.z);
                a6 += wv * bl(xv.w); a7 += wv * bh(xv.w);
            }
        }

        cols[k] = col;
        const unsigned p0 = pk2(tanh_half_clip(a0), tanh_half_clip(a1));
        const unsigned p1 = pk2(tanh_half_clip(a2), tanh_half_clip(a3));
        const unsigned p2 = pk2(tanh_half_clip(a4), tanh_half_clip(a5));
        const unsigned p3 = pk2(tanh_half_clip(a6), tanh_half_clip(a7));
        st0[k] = p0; st1[k] = p1; st2[k] = p2; st3[k] = p3;
    }

    __syncthreads();                            // all gathers done: xs free
    unsigned* osp = (unsigned*)xs;              // 4 planes x E (row pairs)
    #pragma unroll
    for (int k = 0; k < E / NT; ++k) {
        osp[0 * E + cols[k]] = st0[k];
        osp[1 * E + cols[k]] = st1[k];
        osp[2 * E + cols[k]] = st2[k];
        osp[3 * E + cols[k]] = st3[k];
    }
    __syncthreads();

    #pragma unroll
    for (int k = 0; k < E / NT; ++k) {
        const int e = k * NT + t;
        #pragma unroll
        for (int p = 0; p < 4; ++p) {
            const unsigned q = osp[p * E + e];  // coalesced, conflict-free
            out[(size_t)(b0 + 2 * p) * E + e]     = bl(q);
            out[(size_t)(b0 + 2 * p + 1) * E + e] = bh(q);
        }
    }
}

extern "C" void kernel_launch(void* const* d_in, const int* in_sizes, int n_in,
                              void* d_out, int out_size, void* d_ws, size_t ws_size,
                              hipStream_t stream) {
    const float* x        = (const float*)d_in[0];  // [B, E]
    const float* llr      = (const float*)d_in[1];  // [B, NVARS]
    const float* u        = (const float*)d_in[2];  // [E]
    const float* odd_w    = (const float*)d_in[3];  // [E, E]
    const float* llr_w    = (const float*)d_in[4];  // [NVARS, E]
    const float* logits   = (const float*)d_in[5];  // [E]
    // d_in[6] (o2e_mask) not needed: structure derived from skip mask.
    const float* skip_msk = (const float*)d_in[7];  // [NVARS, E]
    float* out = (float*)d_out;

    const int B = in_sizes[0] / E;                  // 16384

    // Workspace (~200 KB), 16B-aligned segments.
    char* wsb = (char*)d_ws;
    size_t off = 0;
    unsigned int*   tbl  = (unsigned int*)(wsb + off); off += (size_t)NBMAX * E * 16; // 163840
    float2*         meta = (float2*)(wsb + off);       off += (size_t)E * 8;          //  16384
    float*          skw  = (float*)(wsb + off);        off += (size_t)E * 4;          //   8192
    unsigned short* vsrc = (unsigned short*)(wsb + off); off += (size_t)E * 2;        //   4096

    k_vsrc <<<dim3(E / 256, 32), dim3(256), 0, stream>>>(skip_msk, llr_w, vsrc, skw);
    k_table<<<dim3(E / 64),      dim3(64),  0, stream>>>(vsrc, skw, odd_w, u, logits,
                                                         tbl, meta);

    fused_main<<<dim3(B / TB), dim3(NT), 0, stream>>>(x, llr, tbl, meta, out);
}

// Round 8
// 116.276 us; speedup vs baseline: 2.1095x; 2.1095x over previous
//
#include <hip/hip_runtime.h>
#include <hip/hip_bf16.h>

constexpr int E     = 2048;   // edges
constexpr int NVARS = 512;    // variable nodes
constexpr int MAXS  = 20;     // max slots per rank (= max var degree supported)
constexpr int NBMAX = MAXS / 4;
constexpr int TB    = 8;      // batch rows per block in main kernel
constexpr int NT    = 512;    // threads per block in main kernel

// RNE float -> bf16 (kept in HIGH 16 bits).
__device__ __forceinline__ unsigned bf16hi(float f) {
    const unsigned uu = __float_as_uint(f);
    return (uu + 0x7FFFu + ((uu >> 16) & 1u)) & 0xFFFF0000u;
}
__device__ __forceinline__ unsigned pk2(float a, float b) {
    return (bf16hi(a) >> 16) | bf16hi(b);
}
__device__ __forceinline__ float bl(unsigned q) { return __uint_as_float(q << 16); }
__device__ __forceinline__ float bh(unsigned q) { return __uint_as_float(q & 0xFFFF0000u); }

// ---------------------------------------------------------------------------
// kA: scan skip mask (4 MB) -> var(e) + fused skip weight. One nonzero per
// column => unique writer. grid (8, 32) x 256 threads, fully coalesced.
// ---------------------------------------------------------------------------
__global__ __launch_bounds__(256)
void k_vsrc(const float* __restrict__ skip_mask,
            const float* __restrict__ llr_w,
            unsigned short* __restrict__ vsrc,
            float* __restrict__ skw)
{
    const int col = blockIdx.x * 256 + threadIdx.x;
    const int v0  = blockIdx.y * (NVARS / 32);     // 16-row stripe
    for (int v = v0; v < v0 + NVARS / 32; ++v) {
        const float m = skip_mask[(size_t)v * E + col];
        if (m != 0.0f) {
            vsrc[col] = (unsigned short)v;
            skw [col] = m * llr_w[(size_t)v * E + col];
        }
    }
}

// ---------------------------------------------------------------------------
// kB: one block (1 wave of 64) PER VARIABLE. Deterministic by construction:
// every block derives identical deg[] and its own vstart from the same vsrc.
// rank(col) = vstart(var) + indexOf(col in ascending-e member list).
// Ranks are contiguous per var, sorted by (deg, var) => wave-uniform nb in
// fused_main. Table slot j of rank r = member j (self/pad slots weight 0).
// ---------------------------------------------------------------------------
__global__ __launch_bounds__(64)
void k_pervar(const unsigned short* __restrict__ vsrc,
              const float* __restrict__ skw,
              const float* __restrict__ odd_w,
              const float* __restrict__ u,
              const float* __restrict__ logits,
              unsigned int* __restrict__ tbl,
              float2* __restrict__ meta)
{
    __shared__ unsigned short vs[E];       // 4 KB
    __shared__ int deg[NVARS];             // 2 KB
    __shared__ unsigned short mem[MAXS];
    __shared__ float zf[MAXS];

    const int v   = blockIdx.x;
    const int tid = threadIdx.x;           // 0..63 (one wave)

    for (int i = tid; i < E / 8; i += 64)
        ((uint4*)vs)[i] = ((const uint4*)vsrc)[i];
    for (int i = tid; i < NVARS; i += 64) deg[i] = 0;
    __syncthreads();
    for (int i = tid; i < E; i += 64) atomicAdd(&deg[vs[i]], 1);
    __syncthreads();

    const int dv = deg[v];
    if (dv == 0) return;

    // vstart = sum of deg(v') with (deg(v'), v') < (dv, v), wave-reduced.
    int acc = 0;
    for (int i = tid; i < NVARS; i += 64) {
        const int d2 = deg[i];
        if (d2 > 0 && (d2 < dv || (d2 == dv && i < v))) acc += d2;
    }
    #pragma unroll
    for (int off = 32; off; off >>= 1) acc += __shfl_xor(acc, off);
    const int vstart = acc;

    // member list: ballot compaction over 32 chunks, ascending e.
    int cnt = 0;
    for (int c = 0; c < E / 64; ++c) {
        const int e = c * 64 + tid;
        const bool m = ((int)vs[e] == v);
        const unsigned long long bal = __ballot(m);
        if (m) {
            const int pos = cnt + __popcll(bal & ((1ull << tid) - 1ull));
            if (pos < MAXS) mem[pos] = (unsigned short)e;
        }
        cnt += __popcll(bal);
    }
    const int d_eff = (cnt < MAXS) ? cnt : MAXS;
    const int nb    = (d_eff + 3) >> 2;
    __syncthreads();

    // per-member dropout gate
    if (tid < d_eff) {
        const int m = mem[tid];
        const float sig = 1.0f / (1.0f + __expf(-logits[m]));
        zf[tid] = (u[m] < sig) ? 1.0f : 0.0f;
    }
    __syncthreads();

    // meta per member i (rank = vstart + i)
    if (tid < d_eff) {
        const int col = mem[tid];
        meta[vstart + tid] =
            make_float2(skw[col], __int_as_float(col | (v << 11) | (nb << 20)));
    }

    // table entries: flattened (member i, slot j) pairs across the wave
    const int nslots = nb * 4;
    for (int idx = tid; idx < d_eff * nslots; idx += 64) {
        const int i   = idx / nslots;
        const int j   = idx - i * nslots;
        const int col = mem[i];
        unsigned ent = 0u;                  // pad / self slot: w = 0
        if (j < d_eff) {
            const int ep = mem[j];
            if (ep != col) {
                const float ww = odd_w[(size_t)ep * E + col] * zf[j];
                ent = bf16hi(ww) | (unsigned)ep;
            }
        }
        tbl[((size_t)(j >> 2) * E + (vstart + i)) * 4 + (j & 3)] = ent;
    }
}

// tanh(0.5*clip(s,-10,10)) = (e^c - 1)/(e^c + 1)
__device__ __forceinline__ float tanh_half_clip(float s) {
    float c = fminf(fmaxf(s, -10.0f), 10.0f);
    float t = __expf(c);
    return (t - 1.0f) * __frcp_rn(t + 1.0f);
}

// ---------------------------------------------------------------------------
// Main fused kernel. TB=8 rows; x/llr staged bf16 (8 rows per uint4 => ONE
// ds_read_b128 per gather entry). Ranks sorted by deg => wave-uniform nb.
// Outputs: stash bf16 pairs in registers, sync, reuse xs as 4 row-pair
// planes, sync, fully coalesced f32 stores. LDS = 40 KB -> 4 blocks/CU.
// ---------------------------------------------------------------------------
__global__ __launch_bounds__(NT, 8)
void fused_main(const float* __restrict__ x,          // [B, E]
                const float* __restrict__ llr,        // [B, NVARS]
                const unsigned int* __restrict__ tbl, // [NBMAX][E] uint4 blocks
                const float2* __restrict__ meta,      // [E] rank-major
                float* __restrict__ out)
{
    __shared__ uint4 xs[E];        // stage: packed x; later: out planes
    __shared__ uint4 ls[NVARS];

    const int b0 = blockIdx.x * TB;
    const int t  = threadIdx.x;

    {
        const float4* xr = (const float4*)(x + (size_t)b0 * E);
        const float4 r0 = xr[0 * (E / 4) + t];
        const float4 r1 = xr[1 * (E / 4) + t];
        const float4 r2 = xr[2 * (E / 4) + t];
        const float4 r3 = xr[3 * (E / 4) + t];
        const float4 r4 = xr[4 * (E / 4) + t];
        const float4 r5 = xr[5 * (E / 4) + t];
        const float4 r6 = xr[6 * (E / 4) + t];
        const float4 r7 = xr[7 * (E / 4) + t];
        xs[4 * t + 0] = make_uint4(pk2(r0.x, r1.x), pk2(r2.x, r3.x),
                                   pk2(r4.x, r5.x), pk2(r6.x, r7.x));
        xs[4 * t + 1] = make_uint4(pk2(r0.y, r1.y), pk2(r2.y, r3.y),
                                   pk2(r4.y, r5.y), pk2(r6.y, r7.y));
        xs[4 * t + 2] = make_uint4(pk2(r0.z, r1.z), pk2(r2.z, r3.z),
                                   pk2(r4.z, r5.z), pk2(r6.z, r7.z));
        xs[4 * t + 3] = make_uint4(pk2(r0.w, r1.w), pk2(r2.w, r3.w),
                                   pk2(r4.w, r5.w), pk2(r6.w, r7.w));
    }
    {
        const float* lr = llr + (size_t)b0 * NVARS;
        ls[t] = make_uint4(pk2(lr[t],             lr[NVARS + t]),
                           pk2(lr[2 * NVARS + t], lr[3 * NVARS + t]),
                           pk2(lr[4 * NVARS + t], lr[5 * NVARS + t]),
                           pk2(lr[6 * NVARS + t], lr[7 * NVARS + t]));
    }
    __syncthreads();

    unsigned st0[4], st1[4], st2[4], st3[4];   // bf16-pair stash per k
    int cols[4];

    #pragma unroll
    for (int k = 0; k < E / NT; ++k) {
        const int rk = k * NT + t;              // rank (sorted by deg)
        const float2 mt = meta[rk];
        const int vc  = __float_as_int(mt.y);
        const int col = vc & 0x7FF;
        const int v   = (vc >> 11) & 0x1FF;
        const int nb  = (vc >> 20) & 0xF;
        const float sk = mt.x;

        const uint4 lv = ls[v];
        float a0 = sk * bl(lv.x), a1 = sk * bh(lv.x);
        float a2 = sk * bl(lv.y), a3 = sk * bh(lv.y);
        float a4 = sk * bl(lv.z), a5 = sk * bh(lv.z);
        float a6 = sk * bl(lv.w), a7 = sk * bh(lv.w);

        const uint4* tq = (const uint4*)tbl + rk;   // coalesced (rank-major)
        for (int ib = 0; ib < nb; ++ib) {
            const uint4 g = tq[(size_t)ib * E];
            #pragma unroll
            for (int q = 0; q < 4; ++q) {
                const unsigned ent = (q == 0) ? g.x : (q == 1) ? g.y
                                   : (q == 2) ? g.z : g.w;
                const float wv = __uint_as_float(ent & 0xFFFF0000u);
                const int   s  = (int)(ent & 0x7FFu);
                const uint4 xv = xs[s];                  // one ds_read_b128
                a0 += wv * bl(xv.x); a1 += wv * bh(xv.x);
                a2 += wv * bl(xv.y); a3 += wv * bh(xv.y);
                a4 += wv * bl(xv.z); a5 += wv * bh(xv.z);
                a6 += wv * bl(xv.w); a7 += wv * bh(xv.w);
            }
        }

        cols[k] = col;
        st0[k] = pk2(tanh_half_clip(a0), tanh_half_clip(a1));
        st1[k] = pk2(tanh_half_clip(a2), tanh_half_clip(a3));
        st2[k] = pk2(tanh_half_clip(a4), tanh_half_clip(a5));
        st3[k] = pk2(tanh_half_clip(a6), tanh_half_clip(a7));
    }

    __syncthreads();                            // all gathers done: xs free
    unsigned* osp = (unsigned*)xs;              // 4 planes x E (row pairs)
    #pragma unroll
    for (int k = 0; k < E / NT; ++k) {
        osp[0 * E + cols[k]] = st0[k];
        osp[1 * E + cols[k]] = st1[k];
        osp[2 * E + cols[k]] = st2[k];
        osp[3 * E + cols[k]] = st3[k];
    }
    __syncthreads();

    #pragma unroll
    for (int k = 0; k < E / NT; ++k) {
        const int e = k * NT + t;
        #pragma unroll
        for (int p = 0; p < 4; ++p) {
            const unsigned q = osp[p * E + e];  // coalesced, conflict-free
            out[(size_t)(b0 + 2 * p) * E + e]     = bl(q);
            out[(size_t)(b0 + 2 * p + 1) * E + e] = bh(q);
        }
    }
}

extern "C" void kernel_launch(void* const* d_in, const int* in_sizes, int n_in,
                              void* d_out, int out_size, void* d_ws, size_t ws_size,
                              hipStream_t stream) {
    const float* x        = (const float*)d_in[0];  // [B, E]
    const float* llr      = (const float*)d_in[1];  // [B, NVARS]
    const float* u        = (const float*)d_in[2];  // [E]
    const float* odd_w    = (const float*)d_in[3];  // [E, E]
    const float* llr_w    = (const float*)d_in[4];  // [NVARS, E]
    const float* logits   = (const float*)d_in[5];  // [E]
    // d_in[6] (o2e_mask) not needed: structure derived from skip mask.
    const float* skip_msk = (const float*)d_in[7];  // [NVARS, E]
    float* out = (float*)d_out;

    const int B = in_sizes[0] / E;                  // 16384

    // Workspace (~192 KB), 16B-aligned segments.
    char* wsb = (char*)d_ws;
    size_t off = 0;
    unsigned int*   tbl  = (unsigned int*)(wsb + off); off += (size_t)NBMAX * E * 16; // 163840
    float2*         meta = (float2*)(wsb + off);       off += (size_t)E * 8;          //  16384
    float*          skw  = (float*)(wsb + off);        off += (size_t)E * 4;          //   8192
    unsigned short* vsrc = (unsigned short*)(wsb + off); off += (size_t)E * 2;        //   4096

    k_vsrc  <<<dim3(E / 256, 32), dim3(256), 0, stream>>>(skip_msk, llr_w, vsrc, skw);
    k_pervar<<<dim3(NVARS),       dim3(64),  0, stream>>>(vsrc, skw, odd_w, u, logits,
                                                          tbl, meta);

    fused_main<<<dim3(B / TB), dim3(NT), 0, stream>>>(x, llr, tbl, meta, out);
}

// Round 9
// 104.679 us; speedup vs baseline: 2.3432x; 1.1108x over previous
//
#include <hip/hip_runtime.h>
#include <hip/hip_bf16.h>

constexpr int E     = 2048;   // edges
constexpr int NVARS = 512;    // variable nodes
constexpr int DMAX  = 20;     // max var degree supported (actual max <= 20, verified R8)
constexpr int TB    = 8;      // batch rows per block in main kernel
constexpr int NT    = 512;    // threads per block in main kernel

// RNE float -> bf16 (kept in HIGH 16 bits).
__device__ __forceinline__ unsigned bf16hi(float f) {
    const unsigned uu = __float_as_uint(f);
    return (uu + 0x7FFFu + ((uu >> 16) & 1u)) & 0xFFFF0000u;
}
__device__ __forceinline__ unsigned pk2(float a, float b) {
    return (bf16hi(a) >> 16) | bf16hi(b);
}
__device__ __forceinline__ float bl(unsigned q) { return __uint_as_float(q << 16); }
__device__ __forceinline__ float bh(unsigned q) { return __uint_as_float(q & 0xFFFF0000u); }

// ---------------------------------------------------------------------------
// kA: scan skip mask (4 MB) -> var(e) + fused skip weight. One nonzero per
// column => unique writer. grid (8, 32) x 256 threads, fully coalesced.
// ---------------------------------------------------------------------------
__global__ __launch_bounds__(256)
void k_vsrc(const float* __restrict__ skip_mask,
            const float* __restrict__ llr_w,
            unsigned short* __restrict__ vsrc,
            float* __restrict__ skw)
{
    const int col = blockIdx.x * 256 + threadIdx.x;
    const int v0  = blockIdx.y * (NVARS / 32);     // 16-row stripe
    for (int v = v0; v < v0 + NVARS / 32; ++v) {
        const float m = skip_mask[(size_t)v * E + col];
        if (m != 0.0f) {
            vsrc[col] = (unsigned short)v;
            skw [col] = m * llr_w[(size_t)v * E + col];
        }
    }
}

// ---------------------------------------------------------------------------
// kB: one wave per variable. Derives deterministic global rank order sorted
// by (deg, var): vstart = sum of deg over smaller (deg,var); group members
// (ascending e) own ranks vstart..vstart+d-1. Emits:
//   meta[rank] = {skw(col), col | var<<11}
//   mcol[rank] = col
//   wt[rank_j*DMAX + i] = bf16( odd_w[e_j, e_i] * z_j ), 0 if i==j
//   itemMeta[item] = vstart | chunk<<11 | d<<14   (chunks of 4 outputs)
//   nitems[0]
// ---------------------------------------------------------------------------
__global__ __launch_bounds__(64)
void k_pervar(const unsigned short* __restrict__ vsrc,
              const float* __restrict__ skw,
              const float* __restrict__ odd_w,
              const float* __restrict__ u,
              const float* __restrict__ logits,
              unsigned short* __restrict__ mcol,
              unsigned short* __restrict__ wt,
              unsigned int*   __restrict__ itemMeta,
              int*            __restrict__ nitems,
              float2*         __restrict__ meta)
{
    __shared__ unsigned short vs[E];       // 4 KB
    __shared__ int deg[NVARS];             // 2 KB
    __shared__ unsigned short mem[DMAX];
    __shared__ float zf[DMAX];

    const int v   = blockIdx.x;
    const int tid = threadIdx.x;           // 0..63 (one wave)

    for (int i = tid; i < E / 8; i += 64)
        ((uint4*)vs)[i] = ((const uint4*)vsrc)[i];
    for (int i = tid; i < NVARS; i += 64) deg[i] = 0;
    __syncthreads();
    for (int i = tid; i < E; i += 64) atomicAdd(&deg[vs[i]], 1);
    __syncthreads();

    const int dv = deg[v];

    // itot (all groups), vstart, ibase — one pass + wave reductions.
    int itot = 0, vst = 0, ib = 0;
    for (int i = tid; i < NVARS; i += 64) {
        const int d2 = deg[i];
        if (!d2) continue;
        const int dc = (d2 < DMAX) ? d2 : DMAX;
        const int ic = (dc + 3) >> 2;
        itot += ic;
        if (dv > 0 && (d2 < dv || (d2 == dv && i < v))) { vst += d2; ib += ic; }
    }
    #pragma unroll
    for (int o = 32; o; o >>= 1) {
        itot += __shfl_xor(itot, o);
        vst  += __shfl_xor(vst,  o);
        ib   += __shfl_xor(ib,   o);
    }
    if (v == 0 && tid == 0) nitems[0] = itot;
    if (!dv) return;
    const int de = (dv < DMAX) ? dv : DMAX;

    // member list: ballot compaction, ascending e (deterministic).
    int cnt = 0;
    for (int c = 0; c < E / 64; ++c) {
        const int e = c * 64 + tid;
        const bool m = ((int)vs[e] == v);
        const unsigned long long bal = __ballot(m);
        if (m) {
            const int pos = cnt + __popcll(bal & ((1ull << tid) - 1ull));
            if (pos < DMAX) mem[pos] = (unsigned short)e;
        }
        cnt += __popcll(bal);
    }
    __syncthreads();

    if (tid < de) {
        const int m = mem[tid];
        const float sig = 1.0f / (1.0f + __expf(-logits[m]));
        zf[tid] = (u[m] < sig) ? 1.0f : 0.0f;
        mcol[vst + tid] = (unsigned short)m;
        meta[vst + tid] = make_float2(skw[m], __int_as_float(m | (v << 11)));
    }
    __syncthreads();

    // weight sub-matrix: wt[(vst+j)*DMAX + i] = w(member j -> output i)
    for (int idx = tid; idx < de * de; idx += 64) {
        const int j = idx / de;
        const int i = idx - j * de;
        float ww = 0.0f;
        if (i != j)
            ww = odd_w[(size_t)mem[j] * E + mem[i]] * zf[j];
        wt[(size_t)(vst + j) * DMAX + i] = (unsigned short)(bf16hi(ww) >> 16);
    }

    const int nch = (de + 3) >> 2;
    if (tid < nch)
        itemMeta[ib + tid] = (unsigned)vst | ((unsigned)tid << 11)
                           | ((unsigned)de << 14);
}

// tanh(0.5*clip(s,-10,10)) = (e^c - 1)/(e^c + 1)
__device__ __forceinline__ float th(float s) {
    float c = fminf(fmaxf(s, -10.0f), 10.0f);
    float t = __expf(c);
    return (t - 1.0f) * __frcp_rn(t + 1.0f);
}

// ---------------------------------------------------------------------------
// Main fused kernel, group-structured. One item = (var-group, chunk of <=4
// outputs). Per item: d ds_read_b128 of member x-vectors serve ALL 4 outputs
// (vs 1 read per entry per output before: ~8x fewer LDS instrs). Weights
// streamed 8B per member from rank-major wt (L2-hot). Outputs stashed as
// bf16 pairs, scattered into reused xs, then stored linearly (coalesced).
// LDS = 40 KB; ~110 VGPR -> 2 blocks/CU.
// ---------------------------------------------------------------------------
__global__ __launch_bounds__(NT, 4)
void fused_main(const float* __restrict__ x,          // [B, E]
                const float* __restrict__ llr,        // [B, NVARS]
                const unsigned short* __restrict__ mcol,
                const unsigned short* __restrict__ wt,
                const unsigned int*   __restrict__ itemMeta,
                const int*            __restrict__ nitems,
                const float2* __restrict__ meta,
                float* __restrict__ out)
{
    __shared__ uint4 xs[E];        // stage: packed x; later: 4 output planes
    __shared__ uint4 ls[NVARS];

    const int b0 = blockIdx.x * TB;
    const int t  = threadIdx.x;

    {
        const float4* xr = (const float4*)(x + (size_t)b0 * E);
        const float4 r0 = xr[0 * (E / 4) + t];
        const float4 r1 = xr[1 * (E / 4) + t];
        const float4 r2 = xr[2 * (E / 4) + t];
        const float4 r3 = xr[3 * (E / 4) + t];
        const float4 r4 = xr[4 * (E / 4) + t];
        const float4 r5 = xr[5 * (E / 4) + t];
        const float4 r6 = xr[6 * (E / 4) + t];
        const float4 r7 = xr[7 * (E / 4) + t];
        xs[4 * t + 0] = make_uint4(pk2(r0.x, r1.x), pk2(r2.x, r3.x),
                                   pk2(r4.x, r5.x), pk2(r6.x, r7.x));
        xs[4 * t + 1] = make_uint4(pk2(r0.y, r1.y), pk2(r2.y, r3.y),
                                   pk2(r4.y, r5.y), pk2(r6.y, r7.y));
        xs[4 * t + 2] = make_uint4(pk2(r0.z, r1.z), pk2(r2.z, r3.z),
                                   pk2(r4.z, r5.z), pk2(r6.z, r7.z));
        xs[4 * t + 3] = make_uint4(pk2(r0.w, r1.w), pk2(r2.w, r3.w),
                                   pk2(r4.w, r5.w), pk2(r6.w, r7.w));
    }
    {
        const float* lr = llr + (size_t)b0 * NVARS;
        ls[t] = make_uint4(pk2(lr[t],             lr[NVARS + t]),
                           pk2(lr[2 * NVARS + t], lr[3 * NVARS + t]),
                           pk2(lr[4 * NVARS + t], lr[5 * NVARS + t]),
                           pk2(lr[6 * NVARS + t], lr[7 * NVARS + t]));
    }
    __syncthreads();

    const int nit = nitems[0];

    unsigned sst[2][4][4];
    int      scol[2][4];
    #pragma unroll
    for (int r = 0; r < 2; ++r)
        #pragma unroll
        for (int ii = 0; ii < 4; ++ii) scol[r][ii] = -1;

    #pragma unroll
    for (int r = 0; r < 2; ++r) {
        const int it = r * NT + t;
        if (it < nit) {
            const unsigned im = itemMeta[it];
            const int base = im & 0x7FF;
            const int o0   = ((im >> 11) & 7) << 2;
            const int d    = (im >> 14) & 31;
            int cnt = d - o0; cnt = (cnt < 4) ? cnt : 4;

            const float2 m0 = meta[base];
            const int v = (__float_as_int(m0.y) >> 11) & 0x1FF;
            const uint4 lvq = ls[v];
            const float lf0 = bl(lvq.x), lf1 = bh(lvq.x);
            const float lf2 = bl(lvq.y), lf3 = bh(lvq.y);
            const float lf4 = bl(lvq.z), lf5 = bh(lvq.z);
            const float lf6 = bl(lvq.w), lf7 = bh(lvq.w);

            float a[4][8];
            int cols4[4];
            #pragma unroll
            for (int ii = 0; ii < 4; ++ii) {
                int idx = base + o0 + ii;
                idx = (idx < E) ? idx : (E - 1);
                const float2 mi = meta[idx];
                cols4[ii] = __float_as_int(mi.y) & 0x7FF;
                const float sk = mi.x;
                a[ii][0] = sk * lf0; a[ii][1] = sk * lf1;
                a[ii][2] = sk * lf2; a[ii][3] = sk * lf3;
                a[ii][4] = sk * lf4; a[ii][5] = sk * lf5;
                a[ii][6] = sk * lf6; a[ii][7] = sk * lf7;
            }

            for (int j = 0; j < d; ++j) {
                const int s = mcol[base + j];
                const uint4 xv = xs[s];                       // ONE b128 / member
                const uint2 wq = *(const uint2*)(wt + (size_t)(base + j) * DMAX + o0);
                const float w0 = bl(wq.x), w1 = bh(wq.x);
                const float w2 = bl(wq.y), w3 = bh(wq.y);
                const float xf0 = bl(xv.x), xf1 = bh(xv.x);
                const float xf2 = bl(xv.y), xf3 = bh(xv.y);
                const float xf4 = bl(xv.z), xf5 = bh(xv.z);
                const float xf6 = bl(xv.w), xf7 = bh(xv.w);
                a[0][0] += w0 * xf0; a[0][1] += w0 * xf1;
                a[0][2] += w0 * xf2; a[0][3] += w0 * xf3;
                a[0][4] += w0 * xf4; a[0][5] += w0 * xf5;
                a[0][6] += w0 * xf6; a[0][7] += w0 * xf7;
                a[1][0] += w1 * xf0; a[1][1] += w1 * xf1;
                a[1][2] += w1 * xf2; a[1][3] += w1 * xf3;
                a[1][4] += w1 * xf4; a[1][5] += w1 * xf5;
                a[1][6] += w1 * xf6; a[1][7] += w1 * xf7;
                a[2][0] += w2 * xf0; a[2][1] += w2 * xf1;
                a[2][2] += w2 * xf2; a[2][3] += w2 * xf3;
                a[2][4] += w2 * xf4; a[2][5] += w2 * xf5;
                a[2][6] += w2 * xf6; a[2][7] += w2 * xf7;
                a[3][0] += w3 * xf0; a[3][1] += w3 * xf1;
                a[3][2] += w3 * xf2; a[3][3] += w3 * xf3;
                a[3][4] += w3 * xf4; a[3][5] += w3 * xf5;
                a[3][6] += w3 * xf6; a[3][7] += w3 * xf7;
            }

            #pragma unroll
            for (int ii = 0; ii < 4; ++ii) {
                if (ii < cnt) {
                    scol[r][ii]   = cols4[ii];
                    sst[r][ii][0] = pk2(th(a[ii][0]), th(a[ii][1]));
                    sst[r][ii][1] = pk2(th(a[ii][2]), th(a[ii][3]));
                    sst[r][ii][2] = pk2(th(a[ii][4]), th(a[ii][5]));
                    sst[r][ii][3] = pk2(th(a[ii][6]), th(a[ii][7]));
                }
            }
        }
    }

    __syncthreads();                            // all gathers done: xs free
    unsigned* osp = (unsigned*)xs;              // 4 planes x E (row pairs)
    #pragma unroll
    for (int r = 0; r < 2; ++r) {
        #pragma unroll
        for (int ii = 0; ii < 4; ++ii) {
            const int c = scol[r][ii];
            if (c >= 0) {
                osp[0 * E + c] = sst[r][ii][0];
                osp[1 * E + c] = sst[r][ii][1];
                osp[2 * E + c] = sst[r][ii][2];
                osp[3 * E + c] = sst[r][ii][3];
            }
        }
    }
    __syncthreads();

    #pragma unroll
    for (int k = 0; k < E / NT; ++k) {
        const int e = k * NT + t;
        #pragma unroll
        for (int p = 0; p < 4; ++p) {
            const unsigned q = osp[p * E + e];  // coalesced linear
            out[(size_t)(b0 + 2 * p) * E + e]     = bl(q);
            out[(size_t)(b0 + 2 * p + 1) * E + e] = bh(q);
        }
    }
}

extern "C" void kernel_launch(void* const* d_in, const int* in_sizes, int n_in,
                              void* d_out, int out_size, void* d_ws, size_t ws_size,
                              hipStream_t stream) {
    const float* x        = (const float*)d_in[0];  // [B, E]
    const float* llr      = (const float*)d_in[1];  // [B, NVARS]
    const float* u        = (const float*)d_in[2];  // [E]
    const float* odd_w    = (const float*)d_in[3];  // [E, E]
    const float* llr_w    = (const float*)d_in[4];  // [NVARS, E]
    const float* logits   = (const float*)d_in[5];  // [E]
    // d_in[6] (o2e_mask) not needed: structure derived from skip mask.
    const float* skip_msk = (const float*)d_in[7];  // [NVARS, E]
    float* out = (float*)d_out;

    const int B = in_sizes[0] / E;                  // 16384

    // Workspace (~120 KB), 16B-aligned segments.
    char* wsb = (char*)d_ws;
    size_t off = 0;
    unsigned short* wt    = (unsigned short*)(wsb + off); off += (size_t)E * DMAX * 2 + 64;  // 81984
    float2*         meta  = (float2*)(wsb + off);         off += (size_t)E * 8;              // 16384
    float*          skw   = (float*)(wsb + off);          off += (size_t)E * 4;              //  8192
    unsigned short* vsrc  = (unsigned short*)(wsb + off); off += (size_t)E * 2;              //  4096
    unsigned short* mcol  = (unsigned short*)(wsb + off); off += (size_t)E * 2 + 64;         //  4160
    unsigned int*   itemM = (unsigned int*)(wsb + off);   off += (size_t)1024 * 4;           //  4096
    int*            nit   = (int*)(wsb + off);            off += 16;

    k_vsrc  <<<dim3(E / 256, 32), dim3(256), 0, stream>>>(skip_msk, llr_w, vsrc, skw);
    k_pervar<<<dim3(NVARS),       dim3(64),  0, stream>>>(vsrc, skw, odd_w, u, logits,
                                                          mcol, wt, itemM, nit, meta);

    fused_main<<<dim3(B / TB), dim3(NT), 0, stream>>>(x, llr, mcol, wt, itemM, nit,
                                                      meta, out);
}

// Round 10
// 96.522 us; speedup vs baseline: 2.5412x; 1.0845x over previous
//
#include <hip/hip_runtime.h>
#include <hip/hip_bf16.h>

constexpr int E     = 2048;   // edges
constexpr int NVARS = 512;    // variable nodes
constexpr int DMAX  = 20;     // max var degree supported (actual max ~14)
constexpr int TB    = 8;      // batch rows per block in main kernel
constexpr int NT    = 512;    // threads per block in main kernel

// RNE float -> bf16 (HIGH 16 bits) — cold-path helper for the builder.
__device__ __forceinline__ unsigned bf16hi(float f) {
    const unsigned uu = __float_as_uint(f);
    return (uu + 0x7FFFu + ((uu >> 16) & 1u)) & 0xFFFF0000u;
}
// hot-path pack: one v_cvt_pk_bf16_f32 (RNE, same rounding as bf16hi)
__device__ __forceinline__ unsigned cvtpk(float lo, float hi) {
    unsigned r;
    asm("v_cvt_pk_bf16_f32 %0, %1, %2" : "=v"(r) : "v"(lo), "v"(hi));
    return r;
}
__device__ __forceinline__ float bl(unsigned q) { return __uint_as_float(q << 16); }
__device__ __forceinline__ float bh(unsigned q) { return __uint_as_float(q & 0xFFFF0000u); }

// ---------------------------------------------------------------------------
// kA: scan skip mask (4 MB) -> var(e) + fused skip weight. One nonzero per
// column => unique writer. grid (8, 32) x 256 threads, fully coalesced.
// ---------------------------------------------------------------------------
__global__ __launch_bounds__(256)
void k_vsrc(const float* __restrict__ skip_mask,
            const float* __restrict__ llr_w,
            unsigned short* __restrict__ vsrc,
            float* __restrict__ skw)
{
    const int col = blockIdx.x * 256 + threadIdx.x;
    const int v0  = blockIdx.y * (NVARS / 32);     // 16-row stripe
    for (int v = v0; v < v0 + NVARS / 32; ++v) {
        const float m = skip_mask[(size_t)v * E + col];
        if (m != 0.0f) {
            vsrc[col] = (unsigned short)v;
            skw [col] = m * llr_w[(size_t)v * E + col];
        }
    }
}

// ---------------------------------------------------------------------------
// kB: one wave per variable. Deterministic: every block derives identical
// deg[] from the same vsrc; bases are prefix sums over (deg,var)-order.
// Emits, per item (= group x chunk-of-4-outputs):
//   hdr[2*item]   = {skw(out0..3)}                      (float4)
//   hdr[2*item+1] = {cols01, cols23, woff, v | d<<16}   (uint4; col sentinel
//                                                        0xFFFF when o >= d)
//   wtc[woff + j] = uint4, component q = bf16(w(member j -> out q))<<16 | src
//   nitems[0]
// ---------------------------------------------------------------------------
__global__ __launch_bounds__(64)
void k_pervar(const unsigned short* __restrict__ vsrc,
              const float* __restrict__ skw,
              const float* __restrict__ odd_w,
              const float* __restrict__ u,
              const float* __restrict__ logits,
              uint4*  __restrict__ wtc,
              float4* __restrict__ hdr,
              int*    __restrict__ nitems)
{
    __shared__ unsigned short vs[E];       // 4 KB
    __shared__ int deg[NVARS];             // 2 KB
    __shared__ unsigned short mem[DMAX];
    __shared__ float zf[DMAX];
    __shared__ float sks[DMAX];

    const int v   = blockIdx.x;
    const int tid = threadIdx.x;           // 0..63 (one wave)

    for (int i = tid; i < E / 8; i += 64)
        ((uint4*)vs)[i] = ((const uint4*)vsrc)[i];
    for (int i = tid; i < NVARS; i += 64) deg[i] = 0;
    __syncthreads();
    for (int i = tid; i < E; i += 64) atomicAdd(&deg[vs[i]], 1);
    __syncthreads();

    const int dv = deg[v];

    // itot / item base / stream base via one pass + wave reductions.
    int itot = 0, ib = 0, wb = 0;
    for (int i = tid; i < NVARS; i += 64) {
        const int d2 = deg[i];
        if (!d2) continue;
        const int dc = (d2 < DMAX) ? d2 : DMAX;
        const int ic = (dc + 3) >> 2;
        itot += ic;
        if (dv > 0 && (d2 < dv || (d2 == dv && i < v))) { ib += ic; wb += dc * ic; }
    }
    #pragma unroll
    for (int o = 32; o; o >>= 1) {
        itot += __shfl_xor(itot, o);
        ib   += __shfl_xor(ib,   o);
        wb   += __shfl_xor(wb,   o);
    }
    if (v == 0 && tid == 0) nitems[0] = itot;
    if (!dv) return;
    const int de = (dv < DMAX) ? dv : DMAX;
    const int ic = (de + 3) >> 2;

    // member list: ballot compaction, ascending e (deterministic).
    int cnt = 0;
    for (int c = 0; c < E / 64; ++c) {
        const int e = c * 64 + tid;
        const bool m = ((int)vs[e] == v);
        const unsigned long long bal = __ballot(m);
        if (m) {
            const int pos = cnt + __popcll(bal & ((1ull << tid) - 1ull));
            if (pos < DMAX) mem[pos] = (unsigned short)e;
        }
        cnt += __popcll(bal);
    }
    __syncthreads();

    if (tid < de) {
        const int m = mem[tid];
        const float sig = 1.0f / (1.0f + __expf(-logits[m]));
        zf [tid] = (u[m] < sig) ? 1.0f : 0.0f;
        sks[tid] = skw[m];
    }
    __syncthreads();

    // headers
    if (tid < ic) {
        const int o0 = tid * 4;
        float s0 = 0, s1 = 0, s2 = 0, s3 = 0;
        unsigned c0 = 0xFFFFu, c1 = 0xFFFFu, c2 = 0xFFFFu, c3 = 0xFFFFu;
        if (o0 + 0 < de) { s0 = sks[o0 + 0]; c0 = mem[o0 + 0]; }
        if (o0 + 1 < de) { s1 = sks[o0 + 1]; c1 = mem[o0 + 1]; }
        if (o0 + 2 < de) { s2 = sks[o0 + 2]; c2 = mem[o0 + 2]; }
        if (o0 + 3 < de) { s3 = sks[o0 + 3]; c3 = mem[o0 + 3]; }
        hdr[2 * (ib + tid)]     = make_float4(s0, s1, s2, s3);
        hdr[2 * (ib + tid) + 1] = make_float4(
            __uint_as_float(c0 | (c1 << 16)),
            __uint_as_float(c2 | (c3 << 16)),
            __uint_as_float((unsigned)(wb + tid * de)),
            __uint_as_float((unsigned)v | ((unsigned)de << 16)));
    }

    // stream: entry (chunk k, member j)
    for (int idx = tid; idx < de * ic; idx += 64) {
        const int k = idx / de;
        const int j = idx - k * de;
        const int src = mem[j];
        unsigned g[4];
        #pragma unroll
        for (int q = 0; q < 4; ++q) {
            const int o = 4 * k + q;
            float ww = 0.0f;
            if (o < de && o != j)
                ww = odd_w[(size_t)src * E + mem[o]] * zf[j];
            g[q] = bf16hi(ww) | (unsigned)src;
        }
        wtc[wb + idx] = make_uint4(g[0], g[1], g[2], g[3]);
    }
}

// tanh(0.5*clip(s,-10,10)) = (e^c - 1)/(e^c + 1)
__device__ __forceinline__ float th(float s) {
    float c = fminf(fmaxf(s, -10.0f), 10.0f);
    float t = __expf(c);
    return (t - 1.0f) * __frcp_rn(t + 1.0f);
}

// ---------------------------------------------------------------------------
// Main fused kernel, group-structured. One item = (var-group, chunk of <=4
// outputs). Per member j: ONE contiguous uint4 stream load (weights + src)
// + ONE ds_read_b128 serving 4 outputs x 8 rows. Outputs stashed as bf16
// pairs, scattered into reused xs planes, stored linearly (coalesced).
// LDS = 40 KB -> 3 blocks/CU at launch_bounds(512,6) = 24 waves/CU.
// ---------------------------------------------------------------------------
__global__ __launch_bounds__(NT, 6)
void fused_main(const float* __restrict__ x,          // [B, E]
                const float* __restrict__ llr,        // [B, NVARS]
                const uint4*  __restrict__ wtc,       // packed weight stream
                const float4* __restrict__ hdr,       // 2 x float4 per item
                const int*    __restrict__ nitems,
                float* __restrict__ out)
{
    __shared__ uint4 xs[E];        // stage: packed x; later: 4 output planes
    __shared__ uint4 ls[NVARS];

    const int b0 = blockIdx.x * TB;
    const int t  = threadIdx.x;

    {
        const float4* xr = (const float4*)(x + (size_t)b0 * E);
        const float4 r0 = xr[0 * (E / 4) + t];
        const float4 r1 = xr[1 * (E / 4) + t];
        const float4 r2 = xr[2 * (E / 4) + t];
        const float4 r3 = xr[3 * (E / 4) + t];
        const float4 r4 = xr[4 * (E / 4) + t];
        const float4 r5 = xr[5 * (E / 4) + t];
        const float4 r6 = xr[6 * (E / 4) + t];
        const float4 r7 = xr[7 * (E / 4) + t];
        xs[4 * t + 0] = make_uint4(cvtpk(r0.x, r1.x), cvtpk(r2.x, r3.x),
                                   cvtpk(r4.x, r5.x), cvtpk(r6.x, r7.x));
        xs[4 * t + 1] = make_uint4(cvtpk(r0.y, r1.y), cvtpk(r2.y, r3.y),
                                   cvtpk(r4.y, r5.y), cvtpk(r6.y, r7.y));
        xs[4 * t + 2] = make_uint4(cvtpk(r0.z, r1.z), cvtpk(r2.z, r3.z),
                                   cvtpk(r4.z, r5.z), cvtpk(r6.z, r7.z));
        xs[4 * t + 3] = make_uint4(cvtpk(r0.w, r1.w), cvtpk(r2.w, r3.w),
                                   cvtpk(r4.w, r5.w), cvtpk(r6.w, r7.w));
    }
    {
        const float* lr = llr + (size_t)b0 * NVARS;
        ls[t] = make_uint4(cvtpk(lr[t],             lr[NVARS + t]),
                           cvtpk(lr[2 * NVARS + t], lr[3 * NVARS + t]),
                           cvtpk(lr[4 * NVARS + t], lr[5 * NVARS + t]),
                           cvtpk(lr[6 * NVARS + t], lr[7 * NVARS + t]));
    }
    __syncthreads();

    const int nit = nitems[0];

    unsigned sst[2][4][4];
    unsigned scc[2][2];                        // packed cols {c01, c23}

    #pragma unroll
    for (int r = 0; r < 2; ++r) {
        scc[r][0] = 0xFFFFFFFFu;
        scc[r][1] = 0xFFFFFFFFu;
        const int it = r * NT + t;
        if (it < nit) {
            const float4 ha = hdr[2 * it];
            const uint4  hb = ((const uint4*)hdr)[2 * it + 1];
            const unsigned woff = hb.z;
            const int v = hb.w & 0xFFFF;
            const int d = hb.w >> 16;

            const uint4 lvq = ls[v];
            const float lf0 = bl(lvq.x), lf1 = bh(lvq.x);
            const float lf2 = bl(lvq.y), lf3 = bh(lvq.y);
            const float lf4 = bl(lvq.z), lf5 = bh(lvq.z);
            const float lf6 = bl(lvq.w), lf7 = bh(lvq.w);

            float a[4][8];
            #pragma unroll
            for (int ii = 0; ii < 4; ++ii) {
                const float sk = (ii == 0) ? ha.x : (ii == 1) ? ha.y
                               : (ii == 2) ? ha.z : ha.w;
                a[ii][0] = sk * lf0; a[ii][1] = sk * lf1;
                a[ii][2] = sk * lf2; a[ii][3] = sk * lf3;
                a[ii][4] = sk * lf4; a[ii][5] = sk * lf5;
                a[ii][6] = sk * lf6; a[ii][7] = sk * lf7;
            }

            const uint4* wp = wtc + woff;
            for (int j = 0; j < d; ++j) {
                const uint4 g = wp[j];                       // contiguous 16B
                const int   s = (int)(g.x & 0x7FFu);
                const uint4 xv = xs[s];                      // one ds_read_b128
                const float w0 = bh(g.x), w1 = bh(g.y);
                const float w2 = bh(g.z), w3 = bh(g.w);
                const float xf0 = bl(xv.x), xf1 = bh(xv.x);
                const float xf2 = bl(xv.y), xf3 = bh(xv.y);
                const float xf4 = bl(xv.z), xf5 = bh(xv.z);
                const float xf6 = bl(xv.w), xf7 = bh(xv.w);
                a[0][0] += w0 * xf0; a[0][1] += w0 * xf1;
                a[0][2] += w0 * xf2; a[0][3] += w0 * xf3;
                a[0][4] += w0 * xf4; a[0][5] += w0 * xf5;
                a[0][6] += w0 * xf6; a[0][7] += w0 * xf7;
                a[1][0] += w1 * xf0; a[1][1] += w1 * xf1;
                a[1][2] += w1 * xf2; a[1][3] += w1 * xf3;
                a[1][4] += w1 * xf4; a[1][5] += w1 * xf5;
                a[1][6] += w1 * xf6; a[1][7] += w1 * xf7;
                a[2][0] += w2 * xf0; a[2][1] += w2 * xf1;
                a[2][2] += w2 * xf2; a[2][3] += w2 * xf3;
                a[2][4] += w2 * xf4; a[2][5] += w2 * xf5;
                a[2][6] += w2 * xf6; a[2][7] += w2 * xf7;
                a[3][0] += w3 * xf0; a[3][1] += w3 * xf1;
                a[3][2] += w3 * xf2; a[3][3] += w3 * xf3;
                a[3][4] += w3 * xf4; a[3][5] += w3 * xf5;
                a[3][6] += w3 * xf6; a[3][7] += w3 * xf7;
            }

            scc[r][0] = hb.x;
            scc[r][1] = hb.y;
            #pragma unroll
            for (int ii = 0; ii < 4; ++ii) {
                sst[r][ii][0] = cvtpk(th(a[ii][0]), th(a[ii][1]));
                sst[r][ii][1] = cvtpk(th(a[ii][2]), th(a[ii][3]));
                sst[r][ii][2] = cvtpk(th(a[ii][4]), th(a[ii][5]));
                sst[r][ii][3] = cvtpk(th(a[ii][6]), th(a[ii][7]));
            }
        }
    }

    __syncthreads();                            // all gathers done: xs free
    unsigned* osp = (unsigned*)xs;              // 4 planes x E (row pairs)
    #pragma unroll
    for (int r = 0; r < 2; ++r) {
        #pragma unroll
        for (int ii = 0; ii < 4; ++ii) {
            const unsigned c = (scc[r][ii >> 1] >> ((ii & 1) * 16)) & 0xFFFFu;
            if (c != 0xFFFFu) {
                osp[0 * E + c] = sst[r][ii][0];
                osp[1 * E + c] = sst[r][ii][1];
                osp[2 * E + c] = sst[r][ii][2];
                osp[3 * E + c] = sst[r][ii][3];
            }
        }
    }
    __syncthreads();

    #pragma unroll
    for (int k = 0; k < E / NT; ++k) {
        const int e = k * NT + t;
        #pragma unroll
        for (int p = 0; p < 4; ++p) {
            const unsigned q = osp[p * E + e];  // coalesced linear
            out[(size_t)(b0 + 2 * p) * E + e]     = bl(q);
            out[(size_t)(b0 + 2 * p + 1) * E + e] = bh(q);
        }
    }
}

extern "C" void kernel_launch(void* const* d_in, const int* in_sizes, int n_in,
                              void* d_out, int out_size, void* d_ws, size_t ws_size,
                              hipStream_t stream) {
    const float* x        = (const float*)d_in[0];  // [B, E]
    const float* llr      = (const float*)d_in[1];  // [B, NVARS]
    const float* u        = (const float*)d_in[2];  // [E]
    const float* odd_w    = (const float*)d_in[3];  // [E, E]
    const float* llr_w    = (const float*)d_in[4];  // [NVARS, E]
    const float* logits   = (const float*)d_in[5];  // [E]
    // d_in[6] (o2e_mask) not needed: structure derived from skip mask.
    const float* skip_msk = (const float*)d_in[7];  // [NVARS, E]
    float* out = (float*)d_out;

    const int B = in_sizes[0] / E;                  // 16384

    // Workspace (~145 KB), 16B-aligned segments.
    char* wsb = (char*)d_ws;
    size_t off = 0;
    uint4*          wtc  = (uint4*)(wsb + off);          off += (size_t)6144 * 16;  // 98304
    float4*         hdr  = (float4*)(wsb + off);         off += (size_t)1024 * 32;  // 32768
    float*          skw  = (float*)(wsb + off);          off += (size_t)E * 4;      //  8192
    unsigned short* vsrc = (unsigned short*)(wsb + off); off += (size_t)E * 2;      //  4096
    int*            nit  = (int*)(wsb + off);            off += 16;

    k_vsrc  <<<dim3(E / 256, 32), dim3(256), 0, stream>>>(skip_msk, llr_w, vsrc, skw);
    k_pervar<<<dim3(NVARS),       dim3(64),  0, stream>>>(vsrc, skw, odd_w, u, logits,
                                                          wtc, hdr, nit);

    fused_main<<<dim3(B / TB), dim3(NT), 0, stream>>>(x, llr, wtc, hdr, nit, out);
}